// Round 14
// baseline (12.721 us; speedup 1.0000x reference)
//
#include <hip/hip_runtime.h>

// Muskingum-Cunge routing, MI355X — single outlet chain (out = Q[15, 2047]).
// Round-14: WARMD 16 -> 8 on the r13 structure (73 WGs x 10 output days,
// steady-state seed). Seeded chunks now warm up entirely inside the 32-step
// exact prologue (32 substeps before first output). Decay calibration from
// r9-r13 (4x bit-identical absmax under warm-up halvings) bounds effective
// rho <~ 0.9/substep -> residual ~ 0.14, under the 0.33 headroom.
// Step machinery byte-identical to r8-r13 (validated absmax 0.875).

#define NROWS   30           // 4 history rows + 18 used days + prefetch pad
#define HDT     10800.0f
#define QMIN2   2e-3f        // 2 * Q_MIN
#define WARMD   8            // warm-up days per chunk (seeded)
#define TDAYS   10           // output days per chunk (73*10 = 730 exact)
#define NBLK    4            // main blocks x 16 steps after the 32-step prologue

__device__ __forceinline__ float dpp0(float x) {
    // lane i <- lane i-1 in rows of 16; lanes 0/16/32/48 get 0 (bound_ctrl)
    return __int_as_float(__builtin_amdgcn_mov_dpp(__float_as_int(x), 0x111, 0xF, 0xF, true));
}
template<int CTRL>
__device__ __forceinline__ float dppsh(float x) {
    // row_shr:N within rows of 16, zero-fill (for prefix sums)
    return __int_as_float(__builtin_amdgcn_mov_dpp(__float_as_int(x), CTRL, 0xF, 0xF, true));
}

__global__ __launch_bounds__(256, 1)
void mc_route(const float* __restrict__ inflow,
              const float* __restrict__ log_n,
              const float* __restrict__ dxs,
              const float* __restrict__ slopes,
              float* __restrict__ out)
{
    __shared__ float lat_s[NROWS * 16];

    const int w      = blockIdx.x;
    const int outb   = w * TDAYS;
    const int dstart = (outb - WARMD) > 0 ? (outb - WARMD) : 0;
    const int tout0  = outb - dstart;    // chunk-local day of first output

    const int tid = threadIdx.x;
    for (int i = tid; i < NROWS * 16; i += 256) {
        const int day = dstart + (i >> 4) - 4;
        float v = 0.0f;
        if ((unsigned)day < 730u)
            v = inflow[day * 32768 + (i & 15) * 2048 + 2047];
        lat_s[i] = v;
    }
    __syncthreads();
    if (tid >= 64) return;       // wave 0 runs the pipeline

    const int lane = tid;
    const int lvl  = lane < 15 ? lane : 15;   // lanes 16..63 ride along (benign)
    const int g    = lvl * 2048 + 2047;
    float* const outw = out + outb;

    const float nman  = expf(log_n[g]);
    const float S     = slopes[g];
    const float dx    = dxs[g];
    const float invA2 = 1.4362848f * nman / __builtin_amdgcn_sqrtf(S);
    const float A     = 0.5f * dx * invA2;
    const float B     = 0.5f * invA2 * invA2 / (7.2f * S);
    const float lKh1  = log2f(A) + 0.2f;   // x = 2*Qref folded in
    const float lKu1  = log2f(B) - 0.1f;

    const float* p0 = lat_s + (5 + ((0 - lvl) >> 2)) * 16 + lvl;
    const float* p1 = lat_s + (5 + ((1 - lvl) >> 2)) * 16 + lvl;
    const float* p2 = lat_s + (5 + ((2 - lvl) >> 2)) * 16 + lvl;
    const float* p3 = lat_s + (5 + ((3 - lvl) >> 2)) * 16 + lvl;

    float b0 = lat_s[(4 + ((0 - lvl) >> 2)) * 16 + lvl];
    float b1 = lat_s[(4 + ((1 - lvl) >> 2)) * 16 + lvl];
    float b2 = lat_s[(4 + ((2 - lvl) >> 2)) * 16 + lvl];
    float b3 = lat_s[(4 + ((3 - lvl) >> 2)) * 16 + lvl];

    // ---- Steady-state seed (only when history is truncated: dstart > 0) ----
    float Q, Iold, xm1, xm2, xm3;
    {
        float s = lat_s[4 * 16 + lane];   // row 4 = day dstart
        s += dppsh<0x111>(s);
        s += dppsh<0x112>(s);
        s += dppsh<0x114>(s);
        s += dppsh<0x118>(s);
        const float seed = (dstart > 0) ? s : 0.0f;
        Q = seed; Iold = seed;
        const float xs = fmaxf(2.0f * seed, QMIN2);
        xm1 = xs; xm2 = xs; xm3 = xs;
    }

// ---------- exact step (reference algebra, r2/r6/r8-validated) ----------
#define STEPX(BUF, LD, ST) do {                                           \
    const float lat = BUF; BUF = (LD);                                    \
    const float up  = dpp0(Q);                                            \
    const float Inew = up + lat;                                          \
    const float x   = fmaxf(Inew + Q, QMIN2);                             \
    const float lg  = __builtin_amdgcn_logf(x);                           \
    const float tKh = fmaf(-0.2f, lg, lKh1);                              \
    const float tKu = fmaf( 0.1f, lg, lKu1);                              \
    const float tmn = fminf(tKu, tKh);                                    \
    const float Kh  = __builtin_amdgcn_exp2f(tKh);                        \
    const float Km  = __builtin_amdgcn_exp2f(tmn);                        \
    const float den = (HDT + Kh) + Km;                                    \
    const float rd  = __builtin_amdgcn_rcpf(den);                         \
    const float Siq = Iold + Q;                                           \
    const float Dif = Iold - Q;                                           \
    const float a1  = fmaf(-2.0f, Kh, den);                               \
    const float a3  = HDT - Km;                                           \
    const float num = fmaf(a1, Inew, fmaf(Kh, Siq, a3 * Dif));            \
    const float Qn2 = fmaxf(num, 0.0f) * rd;                              \
    ST                                                                    \
    xm3 = xm2; xm2 = xm1; xm1 = Inew + Qn2;                               \
    Iold = Inew; Q = Qn2;                                                 \
} while (0);

// ---------- consume one substep with the current set {a1c,khc,a3c,rdc} ----------
#define CONSUME(LATV, POST) do {                                          \
    const float up   = dpp0(Q);                                           \
    const float InewL = up + (LATV);                                      \
    const float Siq  = Iold + Q;                                          \
    const float Dif  = Iold - Q;                                          \
    const float num  = fmaf(a1c, InewL, fmaf(khc, Siq, a3c * Dif));       \
    const float QnL  = fmaxf(num, 0.0f) * rdc;                            \
    POST                                                                  \
    Iold = InewL; Q = QnL;                                                \
} while (0);

// ---------- stage3: fold raw (Kh,Km) into a consume set; rd by Newton x3 ----------
#define STAGE3(KHR, KMR) do {                                             \
    const float den = (HDT + (KHR)) + (KMR);                              \
    float t = fmaf(-den, rdL, 2.0f); float r = rdL * t;                   \
    t = fmaf(-den, r, 2.0f); r = r * t;                                   \
    t = fmaf(-den, r, 2.0f); rdL = r * t;                                 \
    a1c = fmaf(-2.0f, (KHR), den);                                        \
    a3c = HDT - (KMR);                                                    \
    khc = (KHR); rdc = rdL;                                               \
} while (0);

// ---------- one group = 4 substeps, 2 coefficient sets ----------
#define GROUP(OFF, STCODE) do {                                           \
    { /* s0: stage3(A), consume A, log for B */                           \
      const float lat = b0; b0 = p0[OFF];                                 \
      STAGE3(KhRA, KmRA)                                                  \
      CONSUME(lat, {})                                                    \
      lgT = __builtin_amdgcn_logf(fmaxf(xmP, QMIN2)); }                   \
    { /* s1: consume A, record x~, exp2 for B */                          \
      const float lat = b1; b1 = p1[OFF];                                 \
      CONSUME(lat, xmO = InewL + QnL;)                                    \
      const float tKh = fmaf(-0.2f, lgT, lKh1);                           \
      const float tKu = fmaf( 0.1f, lgT, lKu1);                           \
      KhRB = __builtin_amdgcn_exp2f(tKh);                                 \
      KmRB = __builtin_amdgcn_exp2f(fminf(tKu, tKh)); }                   \
    { /* s2: stage3(B), consume B (store), log for next A */              \
      const float lat = b2; b2 = p2[OFF];                                 \
      STAGE3(KhRB, KmRB)                                                  \
      CONSUME(lat, STCODE)                                                \
      lgU = __builtin_amdgcn_logf(fmaxf(xmO, QMIN2)); }                   \
    { /* s3: consume B, record x~, exp2 for next A */                     \
      const float lat = b3; b3 = p3[OFF];                                 \
      CONSUME(lat, xmP = InewL + QnL;)                                    \
      const float tKh = fmaf(-0.2f, lgU, lKh1);                           \
      const float tKu = fmaf( 0.1f, lgU, lKu1);                           \
      KhRA = __builtin_amdgcn_exp2f(tKh);                                 \
      KmRA = __builtin_amdgcn_exp2f(fminf(tKu, tKh)); }                   \
} while (0);

    // ---- Exact prologue: k = 0..31 (covers seeded warm-up + chunk-0 activation) ----
    STEPX(b0, p0[0],  {}) STEPX(b1, p1[0],  {}) STEPX(b2, p2[0],  {}) STEPX(b3, p3[0],  {})
    STEPX(b0, p0[16], {}) STEPX(b1, p1[16], {}) STEPX(b2, p2[16], {}) STEPX(b3, p3[16], {})
    STEPX(b0, p0[32], {}) STEPX(b1, p1[32], {}) STEPX(b2, p2[32], {}) STEPX(b3, p3[32], {})
    STEPX(b0, p0[48], {}) STEPX(b1, p1[48], {}) STEPX(b2, p2[48], {}) STEPX(b3, p3[48], {})
    p0 += 64; p1 += 64; p2 += 64; p3 += 64;
    {
        float4 st;   // local days 0..3 (exact) — stored by chunk 0 only
        STEPX(b0, p0[0],  {}) STEPX(b1, p1[0],  {}) STEPX(b2, p2[0],  st.x = Qn2;) STEPX(b3, p3[0],  {})
        STEPX(b0, p0[16], {}) STEPX(b1, p1[16], {}) STEPX(b2, p2[16], st.y = Qn2;) STEPX(b3, p3[16], {})
        STEPX(b0, p0[32], {}) STEPX(b1, p1[32], {}) STEPX(b2, p2[32], st.z = Qn2;) STEPX(b3, p3[32], {})
        STEPX(b0, p0[48], {}) STEPX(b1, p1[48], {}) STEPX(b2, p2[48], st.w = Qn2;) STEPX(b3, p3[48], {})
        if (lane == 15 && tout0 == 0) *reinterpret_cast<float4*>(outw) = st;
    }
    p0 += 64; p1 += 64; p2 += 64; p3 += 64;

    // ---- Seed the half-rate coefficient pipeline (identical to r8) ----
    float KhRA, KmRA, KhRB, KmRB, rdL;
    float a1c, a3c, khc, rdc;
    float lgT, lgU, xmO, xmP;
    {
        const float lg  = __builtin_amdgcn_logf(fmaxf(xm3, QMIN2));
        const float tKh = fmaf(-0.2f, lg, lKh1);
        const float tKu = fmaf( 0.1f, lg, lKu1);
        KhRA = __builtin_amdgcn_exp2f(tKh);
        KmRA = __builtin_amdgcn_exp2f(fminf(tKu, tKh));
        rdL  = __builtin_amdgcn_rcpf((HDT + KhRA) + KmRA);  // exact seed
        xmP  = xm1;
        KhRB = KhRA; KmRB = KmRA;   // init (overwritten before use)
    }

    // ---- Main: 4 blocks x 4 groups; lane-15 local days tloc = 4..19 ----
    int tloc = 4;
    #pragma unroll 1
    for (int blk = 0; blk < NBLK; ++blk) {
        GROUP(0,  { unsigned d = (unsigned)(tloc + 0 - tout0); if (lane == 15 && d < 10u) outw[d] = QnL; })
        GROUP(16, { unsigned d = (unsigned)(tloc + 1 - tout0); if (lane == 15 && d < 10u) outw[d] = QnL; })
        GROUP(32, { unsigned d = (unsigned)(tloc + 2 - tout0); if (lane == 15 && d < 10u) outw[d] = QnL; })
        GROUP(48, { unsigned d = (unsigned)(tloc + 3 - tout0); if (lane == 15 && d < 10u) outw[d] = QnL; })
        tloc += 4;
        p0 += 64; p1 += 64; p2 += 64; p3 += 64;
    }
#undef GROUP
#undef STAGE3
#undef CONSUME
#undef STEPX
}

extern "C" void kernel_launch(void* const* d_in, const int* in_sizes, int n_in,
                              void* d_out, int out_size, void* d_ws, size_t ws_size,
                              hipStream_t stream) {
    const float* inflow = (const float*)d_in[0];
    const float* log_n  = (const float*)d_in[1];
    const float* dxs    = (const float*)d_in[2];
    const float* slopes = (const float*)d_in[3];
    float* out = (float*)d_out;
    mc_route<<<73, 256, 0, stream>>>(inflow, log_n, dxs, slopes, out);
}

// Round 15
// 12.369 us; speedup vs baseline: 1.0284x; 1.0284x over previous
//
#include <hip/hip_runtime.h>

// Muskingum-Cunge routing, MI355X — single outlet chain (out = Q[15, 2047]).
// FINAL (= round-13 configuration, the empirically best point):
// 73 WGs x 10 output days, WARMD=16 with steady-state seed, 32-step exact
// prologue + 96 lag-pipelined steps. 12.45us / absmax 0.875 (threshold 1.205).
// r14 (WARMD=8) showed the latency floor: fewer steps saved no time and cost
// accuracy headroom. Step machinery validated bit-stable across r8-r13.

#define NROWS   37           // 4 history rows + 26 chunk days + prefetch pad
#define HDT     10800.0f
#define QMIN2   2e-3f        // 2 * Q_MIN
#define WARMD   16           // warm-up days per chunk (seeded)
#define TDAYS   10           // output days per chunk (73*10 = 730 exact)
#define NBLK    6            // main blocks x 16 steps after the 32-step prologue

__device__ __forceinline__ float dpp0(float x) {
    // lane i <- lane i-1 in rows of 16; lanes 0/16/32/48 get 0 (bound_ctrl)
    return __int_as_float(__builtin_amdgcn_mov_dpp(__float_as_int(x), 0x111, 0xF, 0xF, true));
}
template<int CTRL>
__device__ __forceinline__ float dppsh(float x) {
    // row_shr:N within rows of 16, zero-fill (for prefix sums)
    return __int_as_float(__builtin_amdgcn_mov_dpp(__float_as_int(x), CTRL, 0xF, 0xF, true));
}

__global__ __launch_bounds__(256, 1)
void mc_route(const float* __restrict__ inflow,
              const float* __restrict__ log_n,
              const float* __restrict__ dxs,
              const float* __restrict__ slopes,
              float* __restrict__ out)
{
    __shared__ float lat_s[NROWS * 16];

    const int w      = blockIdx.x;
    const int outb   = w * TDAYS;
    const int dstart = (outb - WARMD) > 0 ? (outb - WARMD) : 0;
    const int tout0  = outb - dstart;    // chunk-local day of first output

    const int tid = threadIdx.x;
    for (int i = tid; i < NROWS * 16; i += 256) {
        const int day = dstart + (i >> 4) - 4;
        float v = 0.0f;
        if ((unsigned)day < 730u)
            v = inflow[day * 32768 + (i & 15) * 2048 + 2047];
        lat_s[i] = v;
    }
    __syncthreads();
    if (tid >= 64) return;       // wave 0 runs the pipeline

    const int lane = tid;
    const int lvl  = lane < 15 ? lane : 15;   // lanes 16..63 ride along (benign)
    const int g    = lvl * 2048 + 2047;
    float* const outw = out + outb;

    const float nman  = expf(log_n[g]);
    const float S     = slopes[g];
    const float dx    = dxs[g];
    const float invA2 = 1.4362848f * nman / __builtin_amdgcn_sqrtf(S);
    const float A     = 0.5f * dx * invA2;
    const float B     = 0.5f * invA2 * invA2 / (7.2f * S);
    const float lKh1  = log2f(A) + 0.2f;   // x = 2*Qref folded in
    const float lKu1  = log2f(B) - 0.1f;

    const float* p0 = lat_s + (5 + ((0 - lvl) >> 2)) * 16 + lvl;
    const float* p1 = lat_s + (5 + ((1 - lvl) >> 2)) * 16 + lvl;
    const float* p2 = lat_s + (5 + ((2 - lvl) >> 2)) * 16 + lvl;
    const float* p3 = lat_s + (5 + ((3 - lvl) >> 2)) * 16 + lvl;

    float b0 = lat_s[(4 + ((0 - lvl) >> 2)) * 16 + lvl];
    float b1 = lat_s[(4 + ((1 - lvl) >> 2)) * 16 + lvl];
    float b2 = lat_s[(4 + ((2 - lvl) >> 2)) * 16 + lvl];
    float b3 = lat_s[(4 + ((3 - lvl) >> 2)) * 16 + lvl];

    // ---- Steady-state seed (only when history is truncated: dstart > 0) ----
    float Q, Iold, xm1, xm2, xm3;
    {
        float s = lat_s[4 * 16 + lane];   // row 4 = day dstart
        s += dppsh<0x111>(s);
        s += dppsh<0x112>(s);
        s += dppsh<0x114>(s);
        s += dppsh<0x118>(s);
        const float seed = (dstart > 0) ? s : 0.0f;
        Q = seed; Iold = seed;
        const float xs = fmaxf(2.0f * seed, QMIN2);
        xm1 = xs; xm2 = xs; xm3 = xs;
    }

// ---------- exact step (reference algebra, r2/r6/r8-validated) ----------
#define STEPX(BUF, LD, ST) do {                                           \
    const float lat = BUF; BUF = (LD);                                    \
    const float up  = dpp0(Q);                                            \
    const float Inew = up + lat;                                          \
    const float x   = fmaxf(Inew + Q, QMIN2);                             \
    const float lg  = __builtin_amdgcn_logf(x);                           \
    const float tKh = fmaf(-0.2f, lg, lKh1);                              \
    const float tKu = fmaf( 0.1f, lg, lKu1);                              \
    const float tmn = fminf(tKu, tKh);                                    \
    const float Kh  = __builtin_amdgcn_exp2f(tKh);                        \
    const float Km  = __builtin_amdgcn_exp2f(tmn);                        \
    const float den = (HDT + Kh) + Km;                                    \
    const float rd  = __builtin_amdgcn_rcpf(den);                         \
    const float Siq = Iold + Q;                                           \
    const float Dif = Iold - Q;                                           \
    const float a1  = fmaf(-2.0f, Kh, den);                               \
    const float a3  = HDT - Km;                                           \
    const float num = fmaf(a1, Inew, fmaf(Kh, Siq, a3 * Dif));            \
    const float Qn2 = fmaxf(num, 0.0f) * rd;                              \
    ST                                                                    \
    xm3 = xm2; xm2 = xm1; xm1 = Inew + Qn2;                               \
    Iold = Inew; Q = Qn2;                                                 \
} while (0);

// ---------- consume one substep with the current set {a1c,khc,a3c,rdc} ----------
#define CONSUME(LATV, POST) do {                                          \
    const float up   = dpp0(Q);                                           \
    const float InewL = up + (LATV);                                      \
    const float Siq  = Iold + Q;                                          \
    const float Dif  = Iold - Q;                                          \
    const float num  = fmaf(a1c, InewL, fmaf(khc, Siq, a3c * Dif));       \
    const float QnL  = fmaxf(num, 0.0f) * rdc;                            \
    POST                                                                  \
    Iold = InewL; Q = QnL;                                                \
} while (0);

// ---------- stage3: fold raw (Kh,Km) into a consume set; rd by Newton x3 ----------
#define STAGE3(KHR, KMR) do {                                             \
    const float den = (HDT + (KHR)) + (KMR);                              \
    float t = fmaf(-den, rdL, 2.0f); float r = rdL * t;                   \
    t = fmaf(-den, r, 2.0f); r = r * t;                                   \
    t = fmaf(-den, r, 2.0f); rdL = r * t;                                 \
    a1c = fmaf(-2.0f, (KHR), den);                                        \
    a3c = HDT - (KMR);                                                    \
    khc = (KHR); rdc = rdL;                                               \
} while (0);

// ---------- one group = 4 substeps, 2 coefficient sets ----------
#define GROUP(OFF, STCODE) do {                                           \
    { /* s0: stage3(A), consume A, log for B */                           \
      const float lat = b0; b0 = p0[OFF];                                 \
      STAGE3(KhRA, KmRA)                                                  \
      CONSUME(lat, {})                                                    \
      lgT = __builtin_amdgcn_logf(fmaxf(xmP, QMIN2)); }                   \
    { /* s1: consume A, record x~, exp2 for B */                          \
      const float lat = b1; b1 = p1[OFF];                                 \
      CONSUME(lat, xmO = InewL + QnL;)                                    \
      const float tKh = fmaf(-0.2f, lgT, lKh1);                           \
      const float tKu = fmaf( 0.1f, lgT, lKu1);                           \
      KhRB = __builtin_amdgcn_exp2f(tKh);                                 \
      KmRB = __builtin_amdgcn_exp2f(fminf(tKu, tKh)); }                   \
    { /* s2: stage3(B), consume B (store), log for next A */              \
      const float lat = b2; b2 = p2[OFF];                                 \
      STAGE3(KhRB, KmRB)                                                  \
      CONSUME(lat, STCODE)                                                \
      lgU = __builtin_amdgcn_logf(fmaxf(xmO, QMIN2)); }                   \
    { /* s3: consume B, record x~, exp2 for next A */                     \
      const float lat = b3; b3 = p3[OFF];                                 \
      CONSUME(lat, xmP = InewL + QnL;)                                    \
      const float tKh = fmaf(-0.2f, lgU, lKh1);                           \
      const float tKu = fmaf( 0.1f, lgU, lKu1);                           \
      KhRA = __builtin_amdgcn_exp2f(tKh);                                 \
      KmRA = __builtin_amdgcn_exp2f(fminf(tKu, tKh)); }                   \
} while (0);

    // ---- Exact prologue: k = 0..31 (seeded warm-up / chunk-0 activation) ----
    STEPX(b0, p0[0],  {}) STEPX(b1, p1[0],  {}) STEPX(b2, p2[0],  {}) STEPX(b3, p3[0],  {})
    STEPX(b0, p0[16], {}) STEPX(b1, p1[16], {}) STEPX(b2, p2[16], {}) STEPX(b3, p3[16], {})
    STEPX(b0, p0[32], {}) STEPX(b1, p1[32], {}) STEPX(b2, p2[32], {}) STEPX(b3, p3[32], {})
    STEPX(b0, p0[48], {}) STEPX(b1, p1[48], {}) STEPX(b2, p2[48], {}) STEPX(b3, p3[48], {})
    p0 += 64; p1 += 64; p2 += 64; p3 += 64;
    {
        float4 st;   // local days 0..3 (exact) — stored by chunk 0 only
        STEPX(b0, p0[0],  {}) STEPX(b1, p1[0],  {}) STEPX(b2, p2[0],  st.x = Qn2;) STEPX(b3, p3[0],  {})
        STEPX(b0, p0[16], {}) STEPX(b1, p1[16], {}) STEPX(b2, p2[16], st.y = Qn2;) STEPX(b3, p3[16], {})
        STEPX(b0, p0[32], {}) STEPX(b1, p1[32], {}) STEPX(b2, p2[32], st.z = Qn2;) STEPX(b3, p3[32], {})
        STEPX(b0, p0[48], {}) STEPX(b1, p1[48], {}) STEPX(b2, p2[48], st.w = Qn2;) STEPX(b3, p3[48], {})
        if (lane == 15 && tout0 == 0) *reinterpret_cast<float4*>(outw) = st;
    }
    p0 += 64; p1 += 64; p2 += 64; p3 += 64;

    // ---- Seed the half-rate coefficient pipeline (identical to r8) ----
    float KhRA, KmRA, KhRB, KmRB, rdL;
    float a1c, a3c, khc, rdc;
    float lgT, lgU, xmO, xmP;
    {
        const float lg  = __builtin_amdgcn_logf(fmaxf(xm3, QMIN2));
        const float tKh = fmaf(-0.2f, lg, lKh1);
        const float tKu = fmaf( 0.1f, lg, lKu1);
        KhRA = __builtin_amdgcn_exp2f(tKh);
        KmRA = __builtin_amdgcn_exp2f(fminf(tKu, tKh));
        rdL  = __builtin_amdgcn_rcpf((HDT + KhRA) + KmRA);  // exact seed
        xmP  = xm1;
        KhRB = KhRA; KmRB = KmRA;   // init (overwritten before use)
    }

    // ---- Main: 6 blocks x 4 groups; lane-15 local days tloc = 4..27 ----
    int tloc = 4;
    #pragma unroll 1
    for (int blk = 0; blk < NBLK; ++blk) {
        GROUP(0,  { unsigned d = (unsigned)(tloc + 0 - tout0); if (lane == 15 && d < 10u) outw[d] = QnL; })
        GROUP(16, { unsigned d = (unsigned)(tloc + 1 - tout0); if (lane == 15 && d < 10u) outw[d] = QnL; })
        GROUP(32, { unsigned d = (unsigned)(tloc + 2 - tout0); if (lane == 15 && d < 10u) outw[d] = QnL; })
        GROUP(48, { unsigned d = (unsigned)(tloc + 3 - tout0); if (lane == 15 && d < 10u) outw[d] = QnL; })
        tloc += 4;
        p0 += 64; p1 += 64; p2 += 64; p3 += 64;
    }
#undef GROUP
#undef STAGE3
#undef CONSUME
#undef STEPX
}

extern "C" void kernel_launch(void* const* d_in, const int* in_sizes, int n_in,
                              void* d_out, int out_size, void* d_ws, size_t ws_size,
                              hipStream_t stream) {
    const float* inflow = (const float*)d_in[0];
    const float* log_n  = (const float*)d_in[1];
    const float* dxs    = (const float*)d_in[2];
    const float* slopes = (const float*)d_in[3];
    float* out = (float*)d_out;
    mc_route<<<73, 256, 0, stream>>>(inflow, log_n, dxs, slopes, out);
}